// Round 1
// baseline (106.830 us; speedup 1.0000x reference)
//
#include <hip/hip_runtime.h>

#define DD 128
#define LL 512
#define BB 2
#define Q  4

__device__ __forceinline__ float fast_tanh(float x) {
    // tanh(x) = 1 - 2/(exp(2x)+1); saturates correctly: exp->inf => 1, exp->0 => -1
    float e = __expf(2.0f * x);
    return 1.0f - 2.0f * __builtin_amdgcn_rcpf(e + 1.0f);
}

// Kernel 1: compute sW = s@W and hU = h@U into workspace.
// grid = 2*B*L blocks of 128 threads; one block per output row.
__global__ void proj_kernel(const float* __restrict__ s, const float* __restrict__ h,
                            const float* __restrict__ W, const float* __restrict__ U,
                            float* __restrict__ ws) {
    __shared__ float xrow[DD];
    int bl = blockIdx.x;
    bool second = bl >= (BB * LL);
    int row = second ? (bl - BB * LL) : bl;
    const float* X = second ? h : s;
    const float* M = second ? U : W;
    float* o = ws + (second ? (BB * LL * DD) : 0);

    int t = threadIdx.x;                   // 0..127 = output column
    xrow[t] = X[row * DD + t];
    __syncthreads();

    float acc = 0.0f;
#pragma unroll 8
    for (int d = 0; d < DD; ++d)
        acc = fmaf(xrow[d], M[d * DD + t], acc);
    o[row * DD + t] = acc;
}

// Kernel 2: per block = 4 queries of one batch. 512 threads (8 waves).
// Phase 1: scores[q][j] = sum_d tanh(sW[q][d]+hU[j][d]) * v[d]
// Phase 2: softmax over j
// Phase 3: out[q][d] = sum_j attn[q][j] * h[j][d]
__global__ __launch_bounds__(512, 1)
void attn_kernel(const float* __restrict__ sw, const float* __restrict__ hu,
                 const float* __restrict__ h, const float* __restrict__ v,
                 float* __restrict__ out) {
    __shared__ float sW_lds[Q][DD];        // 2 KB
    __shared__ float v_lds[DD];            // 0.5 KB
    __shared__ float sc[Q][LL];            // 8 KB: scores, then attn (in place)
    __shared__ float red[16][Q][DD];       // 32 KB: PV partial reduce
    __shared__ float wred[Q][8];           // softmax wave partials (max)
    __shared__ float wred2[Q][8];          // softmax wave partials (sum)

    int bl = blockIdx.x;                   // 0..255
    int b = bl >> 7;                       // / (L/Q)
    int i0 = (bl & 127) * Q;
    int t = threadIdx.x;
    int lane = t & 63, wave = t >> 6;

    // ---- load sW rows for the 4 queries + v ----
    {
        int q = t >> 7, d = t & 127;
        sW_lds[q][d] = sw[((b * LL) + i0 + q) * DD + d];
        if (t < DD) v_lds[t] = v[t];
    }
    __syncthreads();

    // ---- phase 1: scores ----
    int half = lane >> 5, sub = lane & 31; // half-wave handles one key; lane covers 4 d's
    int d4 = sub * 4;
    const float* huB = hu + b * LL * DD;
    float4 vv = *(const float4*)&v_lds[d4];
    float4 sw4[Q];
#pragma unroll
    for (int q = 0; q < Q; ++q) sw4[q] = *(const float4*)&sW_lds[q][d4];

    // 8 waves * 2 keys/wave = 16 keys per iteration, 32 iterations
    float4 hu4 = *(const float4*)&huB[(wave * 2 + half) * DD + d4];
    for (int it = 0; it < 32; ++it) {
        float4 cur = hu4;
        if (it < 31) {
            int jn = (it + 1) * 16 + wave * 2 + half;
            hu4 = *(const float4*)&huB[jn * DD + d4];
        }
        int j = it * 16 + wave * 2 + half;
#pragma unroll
        for (int q = 0; q < Q; ++q) {
            float p = fast_tanh(sw4[q].x + cur.x) * vv.x
                    + fast_tanh(sw4[q].y + cur.y) * vv.y
                    + fast_tanh(sw4[q].z + cur.z) * vv.z
                    + fast_tanh(sw4[q].w + cur.w) * vv.w;
            // butterfly within the 32-lane half (xor bits < 32 never cross halves)
            p += __shfl_xor(p, 1);
            p += __shfl_xor(p, 2);
            p += __shfl_xor(p, 4);
            p += __shfl_xor(p, 8);
            p += __shfl_xor(p, 16);
            if (sub == 0) sc[q][j] = p;
        }
    }
    __syncthreads();

    // ---- phase 2: softmax over keys (512 threads -> 1 score per q each) ----
    float x0[Q];
#pragma unroll
    for (int q = 0; q < Q; ++q) x0[q] = sc[q][t];
#pragma unroll
    for (int q = 0; q < Q; ++q) {
        float m = x0[q];
        m = fmaxf(m, __shfl_xor(m, 32));
        m = fmaxf(m, __shfl_xor(m, 16));
        m = fmaxf(m, __shfl_xor(m, 8));
        m = fmaxf(m, __shfl_xor(m, 4));
        m = fmaxf(m, __shfl_xor(m, 2));
        m = fmaxf(m, __shfl_xor(m, 1));
        if (lane == 0) wred[q][wave] = m;
    }
    __syncthreads();
#pragma unroll
    for (int q = 0; q < Q; ++q) {
        float m = wred[q][0];
#pragma unroll
        for (int w = 1; w < 8; ++w) m = fmaxf(m, wred[q][w]);
        x0[q] = __expf(x0[q] - m);
    }
#pragma unroll
    for (int q = 0; q < Q; ++q) {
        float sm = x0[q];
        sm += __shfl_xor(sm, 32);
        sm += __shfl_xor(sm, 16);
        sm += __shfl_xor(sm, 8);
        sm += __shfl_xor(sm, 4);
        sm += __shfl_xor(sm, 2);
        sm += __shfl_xor(sm, 1);
        if (lane == 0) wred2[q][wave] = sm;
    }
    __syncthreads();
#pragma unroll
    for (int q = 0; q < Q; ++q) {
        float sm = 0.0f;
#pragma unroll
        for (int w = 0; w < 8; ++w) sm += wred2[q][w];
        sc[q][t] = x0[q] * __builtin_amdgcn_rcpf(sm);   // attn weight
    }
    __syncthreads();

    // ---- phase 3: out[q][d] = sum_j attn[q][j] * h[j][d] ----
    int sub32 = t & 31, ph = t >> 5;       // ph 0..15
    int dd = sub32 * 4;
    const float* hB = h + b * LL * DD;
    float4 acc[Q];
#pragma unroll
    for (int q = 0; q < Q; ++q) acc[q] = make_float4(0.f, 0.f, 0.f, 0.f);

    for (int jj = 0; jj < 32; ++jj) {
        int j = jj * 16 + ph;
        float4 h4 = *(const float4*)&hB[j * DD + dd];
#pragma unroll
        for (int q = 0; q < Q; ++q) {
            float a = sc[q][j];
            acc[q].x = fmaf(a, h4.x, acc[q].x);
            acc[q].y = fmaf(a, h4.y, acc[q].y);
            acc[q].z = fmaf(a, h4.z, acc[q].z);
            acc[q].w = fmaf(a, h4.w, acc[q].w);
        }
    }
#pragma unroll
    for (int q = 0; q < Q; ++q)
        *(float4*)&red[ph][q][dd] = acc[q];
    __syncthreads();
    {
        int q = t >> 7, d = t & 127;
        float s0 = 0.0f;
#pragma unroll
        for (int p = 0; p < 16; ++p) s0 += red[p][q][d];
        out[((b * LL) + i0 + q) * DD + d] = s0;
    }
}

extern "C" void kernel_launch(void* const* d_in, const int* in_sizes, int n_in,
                              void* d_out, int out_size, void* d_ws, size_t ws_size,
                              hipStream_t stream) {
    const float* s = (const float*)d_in[0];
    const float* h = (const float*)d_in[1];
    const float* W = (const float*)d_in[2];
    const float* U = (const float*)d_in[3];
    const float* v = (const float*)d_in[4];
    float* out = (float*)d_out;
    float* ws  = (float*)d_ws;

    float* swB = ws;                        // B*L*D floats = 512 KB
    float* huB = ws + BB * LL * DD;         // another 512 KB

    hipLaunchKernelGGL(proj_kernel, dim3(2 * BB * LL), dim3(DD), 0, stream,
                       s, h, W, U, ws);
    hipLaunchKernelGGL(attn_kernel, dim3((BB * LL) / Q), dim3(512), 0, stream,
                       swB, huB, h, v, out);
}

// Round 2
// 103.654 us; speedup vs baseline: 1.0306x; 1.0306x over previous
//
#include <hip/hip_runtime.h>

#define DD 128
#define LL 512
#define BB 2
#define NQ 4        // queries per attn block
#define NS 4        // key splits
#define SPL 128     // keys per split (LL/NS)

__device__ __forceinline__ float fast_tanh(float x) {
    // tanh(x) = 1 - 2/(exp(2x)+1); saturates correctly at +/-inf
    float e = __expf(2.0f * x);
    return 1.0f - 2.0f * __builtin_amdgcn_rcpf(e + 1.0f);
}

// ---- Kernel 1: sW = s@W, hU = h@U. 512 blocks x 256 threads, 4 rows/block.
__global__ __launch_bounds__(256)
void proj_kernel(const float* __restrict__ s, const float* __restrict__ h,
                 const float* __restrict__ W, const float* __restrict__ U,
                 float* __restrict__ swB, float* __restrict__ huB) {
    __shared__ float xr[4 * DD];
    int bx = blockIdx.x;
    bool second = bx >= 256;
    const float* X = second ? h : s;
    const float* M = second ? U : W;
    float* O = second ? huB : swB;
    int row0 = (bx & 255) * 4;
    int t = threadIdx.x;
    xr[t]       = X[row0 * DD + t];
    xr[t + 256] = X[row0 * DD + 256 + t];
    __syncthreads();
    int c = t & 127, g = t >> 7;
    const float* x0 = &xr[(2 * g) * DD];
    const float* x1 = &xr[(2 * g + 1) * DD];
    float a0 = 0.f, a1 = 0.f;
#pragma unroll 8
    for (int d = 0; d < DD; ++d) {
        float m = M[d * DD + c];              // coalesced across threads, L1/L2-hit
        a0 = fmaf(x0[d], m, a0);              // LDS broadcast (wave-uniform d)
        a1 = fmaf(x1[d], m, a1);
    }
    O[(row0 + 2 * g) * DD + c]     = a0;
    O[(row0 + 2 * g + 1) * DD + c] = a1;
}

// ---- Kernel 2: flash-style split attention.
// grid = 1024 = 256 query-groups x 4 key-splits; block = 512 threads (8 waves).
// Wave w: q = w>>1, half = w&1; lane owns key jl = half*64+lane.
// Phase 1: score via serial d-loop, NO cross-lane ops in hot loop.
// Phase 3: partial PV into workspace; combine kernel normalizes.
__global__ __launch_bounds__(512, 4)
void attn_split_kernel(const float* __restrict__ swB, const float* __restrict__ huB,
                       const float* __restrict__ h, const float* __restrict__ v,
                       float* __restrict__ opart, float* __restrict__ lsum) {
    __shared__ float sw_lds[NQ * DD];     // 2 KB
    __shared__ float v_lds[DD];           // 0.5 KB
    __shared__ float p_lds[NQ][SPL];      // 2 KB  (exp(score), unnormalized)
    __shared__ float wred[NQ][2];         // per-(q,half) exp-sums
    __shared__ float red[8][NQ][DD];      // 16 KB (PV partial reduce)

    int bx = blockIdx.x;
    int qg = bx >> 2;                     // 0..255
    int split = bx & 3;
    int b = qg >> 7;
    int row0 = qg * 4;                    // global query row base (b*L + i0)
    int t = threadIdx.x;
    int lane = t & 63, w = t >> 6;
    int q = w >> 1, half = w & 1;

    sw_lds[t] = swB[row0 * DD + t];       // 4 rows x 128 = 512
    if (t < DD) v_lds[t] = v[t];
    __syncthreads();

    // ---- phase 1: score[q][jl] ----
    int jl = half * 64 + lane;
    const float4* hp = (const float4*)(huB + (size_t)(b * LL + split * SPL + jl) * DD);
    const float4* sp = (const float4*)(sw_lds + q * DD);   // wave-uniform broadcasts
    const float4* vp = (const float4*)v_lds;
    float acc0 = 0.f, acc1 = 0.f;
#pragma unroll 4
    for (int dt = 0; dt < 32; ++dt) {
        float4 hv = hp[dt];               // per-lane stream, L1-resident lines
        float4 sv = sp[dt];
        float4 vv = vp[dt];
        acc0 = fmaf(fast_tanh(sv.x + hv.x), vv.x, acc0);
        acc1 = fmaf(fast_tanh(sv.y + hv.y), vv.y, acc1);
        acc0 = fmaf(fast_tanh(sv.z + hv.z), vv.z, acc0);
        acc1 = fmaf(fast_tanh(sv.w + hv.w), vv.w, acc1);
    }
    // no max-subtraction: |score| <= ||v||_1 ~ 9, exp() safe in fp32
    float p = __expf(acc0 + acc1);
    p_lds[q][jl] = p;
    float sm = p;
#pragma unroll
    for (int o = 1; o < 64; o <<= 1) sm += __shfl_xor(sm, o);  // once per wave only
    if (lane == 0) wred[q][half] = sm;
    __syncthreads();

    if (t < NQ) lsum[(row0 + t) * NS + split] = wred[t][0] + wred[t][1];

    // ---- phase 3: partial PV. wave w handles keys [w*16, w*16+16), lane covers d2=lane*2.
    const float* hb = h + (size_t)(b * LL + split * SPL) * DD;
    float2 pacc[NQ];
#pragma unroll
    for (int qq = 0; qq < NQ; ++qq) pacc[qq] = make_float2(0.f, 0.f);
    int j0 = w * 16;
    int d2 = lane * 2;
#pragma unroll 4
    for (int jj = 0; jj < 16; ++jj) {
        float2 hv = *(const float2*)&hb[(j0 + jj) * DD + d2];   // coalesced
#pragma unroll
        for (int qq = 0; qq < NQ; ++qq) {
            float pb = p_lds[qq][j0 + jj];                      // broadcast
            pacc[qq].x = fmaf(pb, hv.x, pacc[qq].x);
            pacc[qq].y = fmaf(pb, hv.y, pacc[qq].y);
        }
    }
#pragma unroll
    for (int qq = 0; qq < NQ; ++qq)
        *(float2*)&red[w][qq][d2] = pacc[qq];
    __syncthreads();
    {
        int qq = t >> 7, d = t & 127;
        float o = 0.f;
#pragma unroll
        for (int k = 0; k < 8; ++k) o += red[k][qq][d];
        opart[((size_t)(row0 + qq) * NS + split) * DD + d] = o;
    }
}

// ---- Kernel 3: combine splits. 256 blocks x 512 threads, 4 rows/block.
__global__ __launch_bounds__(512)
void combine_kernel(const float* __restrict__ opart, const float* __restrict__ lsum,
                    float* __restrict__ out) {
    int t = threadIdx.x;
    int r = blockIdx.x * 4 + (t >> 7);
    int d = t & 127;
    float o = 0.f, l = 0.f;
#pragma unroll
    for (int ss = 0; ss < NS; ++ss) {
        o += opart[((size_t)r * NS + ss) * DD + d];
        l += lsum[r * NS + ss];
    }
    out[r * DD + d] = o * __builtin_amdgcn_rcpf(l);
}

extern "C" void kernel_launch(void* const* d_in, const int* in_sizes, int n_in,
                              void* d_out, int out_size, void* d_ws, size_t ws_size,
                              hipStream_t stream) {
    const float* s = (const float*)d_in[0];
    const float* h = (const float*)d_in[1];
    const float* W = (const float*)d_in[2];
    const float* U = (const float*)d_in[3];
    const float* v = (const float*)d_in[4];
    float* out = (float*)d_out;
    float* ws  = (float*)d_ws;

    float* swB   = ws;                      // 1024*128      = 131072 floats
    float* huB   = ws + 131072;             // 1024*128
    float* opart = ws + 262144;             // 1024*4*128    = 524288
    float* lsum  = ws + 786432;             // 1024*4        = 4096   (~3.1 MB total)

    hipLaunchKernelGGL(proj_kernel, dim3(512), dim3(256), 0, stream,
                       s, h, W, U, swB, huB);
    hipLaunchKernelGGL(attn_split_kernel, dim3((BB * LL / NQ) * NS), dim3(512), 0, stream,
                       swB, huB, h, v, opart, lsum);
    hipLaunchKernelGGL(combine_kernel, dim3(256), dim3(512), 0, stream,
                       opart, lsum, out);
}

// Round 3
// 92.527 us; speedup vs baseline: 1.1546x; 1.1203x over previous
//
#include <hip/hip_runtime.h>

#define DD 128
#define LL 512
#define BB 2
#define NK (BB * LL)   // 1024 total rows
#define NQ 4           // queries per attn block
#define NS 4           // key splits
#define SPL 128        // keys per split (LL/NS)

__device__ __forceinline__ float fast_tanh(float x) {
    // tanh(x) = 1 - 2/(exp(2x)+1); saturates correctly at +/-inf
    float e = __expf(2.0f * x);
    return 1.0f - 2.0f * __builtin_amdgcn_rcpf(e + 1.0f);
}

// ---- Kernel 1: swB = s@W (row-major), huT = (h@U)^T (d-major: huT[d][key]).
// 512 blocks x 256 threads, 4 rows/block.
__global__ __launch_bounds__(256)
void proj_kernel(const float* __restrict__ s, const float* __restrict__ h,
                 const float* __restrict__ W, const float* __restrict__ U,
                 float* __restrict__ swB, float* __restrict__ huT) {
    __shared__ float xr[4 * DD];
    int bx = blockIdx.x;
    bool second = bx >= 256;
    const float* X = second ? h : s;
    const float* M = second ? U : W;
    int row0 = (bx & 255) * 4;
    int t = threadIdx.x;
    xr[t]       = X[row0 * DD + t];
    xr[t + 256] = X[row0 * DD + 256 + t];
    __syncthreads();
    int c = t & 127, g = t >> 7;
    const float* x0 = &xr[(2 * g) * DD];
    const float* x1 = &xr[(2 * g + 1) * DD];
    float a0 = 0.f, a1 = 0.f;
#pragma unroll 8
    for (int d = 0; d < DD; ++d) {
        float m = M[d * DD + c];              // coalesced, L2-resident (64 KB)
        a0 = fmaf(x0[d], m, a0);              // LDS broadcast
        a1 = fmaf(x1[d], m, a1);
    }
    if (!second) {
        swB[(row0 + 2 * g) * DD + c]     = a0;
        swB[(row0 + 2 * g + 1) * DD + c] = a1;
    } else {
        // transposed store: column c, rows row0+2g, +1 (adjacent -> float2)
        *(float2*)&huT[c * NK + row0 + 2 * g] = make_float2(a0, a1);
    }
}

// ---- Kernel 2: flash-style split attention, transposed-hU phase 1.
// grid = 1024 = 256 query-groups x 4 key-splits; block = 512 threads (8 waves).
// Wave w: q = w>>1, half = w&1; lane owns key jl = half*64+lane.
__global__ __launch_bounds__(512, 8)
void attn_split_kernel(const float* __restrict__ swB, const float* __restrict__ huT,
                       const float* __restrict__ h, const float* __restrict__ v,
                       float* __restrict__ opart, float* __restrict__ lsum) {
    __shared__ float sw_lds[NQ * DD];     // 2 KB
    __shared__ float v_lds[DD];           // 0.5 KB
    __shared__ float p_lds[NQ][SPL];      // 2 KB  (exp(score), unnormalized)
    __shared__ float wred[NQ][2];         // per-(q,half) exp-sums
    __shared__ float red[8][NQ][DD];      // 16 KB (PV partial reduce)

    int bx = blockIdx.x;
    int qg = bx >> 2;                     // 0..255
    int split = bx & 3;
    int b = qg >> 7;
    int row0 = qg * 4;                    // global query row base (b*L + i0)
    int t = threadIdx.x;
    int lane = t & 63, w = t >> 6;
    int q = w >> 1, half = w & 1;

    sw_lds[t] = swB[row0 * DD + t];
    if (t < DD) v_lds[t] = v[t];
    __syncthreads();

    // ---- phase 1: score[q][jl], coalesced d-major hU reads ----
    int jl = half * 64 + lane;
    int kk = b * LL + split * SPL + jl;   // global key row
    const float* hT = huT + kk;           // column base, stride NK per d
    const float4* sp = (const float4*)(sw_lds + q * DD);
    const float4* vp = (const float4*)v_lds;
    float acc = 0.f;
#pragma unroll 4
    for (int d4 = 0; d4 < 32; ++d4) {
        float4 sv = sp[d4];               // wave-uniform LDS broadcast
        float4 vv = vp[d4];
        float h0 = hT[(d4 * 4 + 0) * NK]; // 64 consecutive dwords per wave
        float h1 = hT[(d4 * 4 + 1) * NK];
        float h2 = hT[(d4 * 4 + 2) * NK];
        float h3 = hT[(d4 * 4 + 3) * NK];
        acc = fmaf(fast_tanh(sv.x + h0), vv.x, acc);
        acc = fmaf(fast_tanh(sv.y + h1), vv.y, acc);
        acc = fmaf(fast_tanh(sv.z + h2), vv.z, acc);
        acc = fmaf(fast_tanh(sv.w + h3), vv.w, acc);
    }
    // no max-subtraction: |score| <= ||v||_1 ~ 9, exp() safe in fp32
    float p = __expf(acc);
    p_lds[q][jl] = p;
    float sm = p;
#pragma unroll
    for (int o = 1; o < 64; o <<= 1) sm += __shfl_xor(sm, o);  // once per wave
    if (lane == 0) wred[q][half] = sm;
    __syncthreads();

    if (t < NQ) lsum[(row0 + t) * NS + split] = wred[t][0] + wred[t][1];

    // ---- phase 3: partial PV. wave w: keys [w*16, w*16+16), lane covers d2=lane*2.
    const float* hb = h + (size_t)(b * LL + split * SPL) * DD;
    float2 pacc[NQ];
#pragma unroll
    for (int qq = 0; qq < NQ; ++qq) pacc[qq] = make_float2(0.f, 0.f);
    int j0 = w * 16;
    int d2 = lane * 2;
#pragma unroll 4
    for (int jj = 0; jj < 16; ++jj) {
        float2 hv = *(const float2*)&hb[(j0 + jj) * DD + d2];   // coalesced
#pragma unroll
        for (int qq = 0; qq < NQ; ++qq) {
            float pb = p_lds[qq][j0 + jj];                      // broadcast
            pacc[qq].x = fmaf(pb, hv.x, pacc[qq].x);
            pacc[qq].y = fmaf(pb, hv.y, pacc[qq].y);
        }
    }
#pragma unroll
    for (int qq = 0; qq < NQ; ++qq)
        *(float2*)&red[w][qq][d2] = pacc[qq];
    __syncthreads();
    {
        int qq = t >> 7, d = t & 127;
        float o = 0.f;
#pragma unroll
        for (int k = 0; k < 8; ++k) o += red[k][qq][d];
        opart[((size_t)(row0 + qq) * NS + split) * DD + d] = o;
    }
}

// ---- Kernel 3: combine splits. 256 blocks x 512 threads, 4 rows/block.
__global__ __launch_bounds__(512)
void combine_kernel(const float* __restrict__ opart, const float* __restrict__ lsum,
                    float* __restrict__ out) {
    int t = threadIdx.x;
    int r = blockIdx.x * 4 + (t >> 7);
    int d = t & 127;
    float o = 0.f, l = 0.f;
#pragma unroll
    for (int ss = 0; ss < NS; ++ss) {
        o += opart[((size_t)r * NS + ss) * DD + d];
        l += lsum[r * NS + ss];
    }
    out[r * DD + d] = o * __builtin_amdgcn_rcpf(l);
}

extern "C" void kernel_launch(void* const* d_in, const int* in_sizes, int n_in,
                              void* d_out, int out_size, void* d_ws, size_t ws_size,
                              hipStream_t stream) {
    const float* s = (const float*)d_in[0];
    const float* h = (const float*)d_in[1];
    const float* W = (const float*)d_in[2];
    const float* U = (const float*)d_in[3];
    const float* v = (const float*)d_in[4];
    float* out = (float*)d_out;
    float* ws  = (float*)d_ws;

    float* swB   = ws;                      // 1024*128   = 131072 floats
    float* huT   = ws + 131072;             // 128*1024 (transposed)
    float* opart = ws + 262144;             // 1024*4*128 = 524288
    float* lsum  = ws + 786432;             // 1024*4     = 4096

    hipLaunchKernelGGL(proj_kernel, dim3(512), dim3(256), 0, stream,
                       s, h, W, U, swB, huT);
    hipLaunchKernelGGL(attn_split_kernel, dim3((BB * LL / NQ) * NS), dim3(512), 0, stream,
                       swB, huT, h, v, opart, lsum);
    hipLaunchKernelGGL(combine_kernel, dim3(256), dim3(512), 0, stream,
                       opart, lsum, out);
}

// Round 4
// 86.095 us; speedup vs baseline: 1.2408x; 1.0747x over previous
//
#include <hip/hip_runtime.h>

#define DD 128
#define LL 512
#define BB 2
#define NK (BB * LL)   // 1024 global rows

// ---- Kernel 1: swB = 2*(s@W) row-major; huT4 = 2*(h@U) tiled [d>>2][key][d&3].
// Pre-scale by 2 folds the tanh's exp(2x) into exp(arg). 512 blocks x 256 thr.
__global__ __launch_bounds__(256)
void proj_kernel(const float* __restrict__ s, const float* __restrict__ h,
                 const float* __restrict__ W, const float* __restrict__ U,
                 float* __restrict__ swB, float* __restrict__ huT4) {
    __shared__ float xr[4 * DD];
    int bx = blockIdx.x;
    bool second = bx >= 256;
    const float* X = second ? h : s;
    const float* M = second ? U : W;
    int row0 = (bx & 255) * 4;            // global row (b*L + i)
    int t = threadIdx.x;
    xr[t]       = X[row0 * DD + t];
    xr[t + 256] = X[row0 * DD + 256 + t];
    __syncthreads();
    int c = t & 127, g = t >> 7;
    const float* x0 = &xr[(2 * g) * DD];
    const float* x1 = &xr[(2 * g + 1) * DD];
    float a0 = 0.f, a1 = 0.f;
#pragma unroll 8
    for (int d = 0; d < DD; ++d) {
        float m = M[d * DD + c];          // coalesced, L2-resident
        a0 = fmaf(x0[d], m, a0);
        a1 = fmaf(x1[d], m, a1);
    }
    a0 *= 2.0f; a1 *= 2.0f;
    if (!second) {
        swB[(row0 + 2 * g) * DD + c]     = a0;
        swB[(row0 + 2 * g + 1) * DD + c] = a1;
    } else {
        int base = (c >> 2) * (NK * 4) + (c & 3);   // tiled transpose
        huT4[base + (row0 + 2 * g) * 4]     = a0;
        huT4[base + (row0 + 2 * g + 1) * 4] = a1;
    }
}

// ---- Kernel 2: fused attention. Block = 2 queries x all 512 keys, 512 thr (8 waves).
// Wave w owns keys [w*64, w*64+64), 1 key/lane, computes BOTH queries per h-load.
// No LDS in phase-1 hot loop: sW/v via uniform (s_load) reads, hU via dwordx4.
__global__ __launch_bounds__(512, 4)
void attn_kernel(const float* __restrict__ swB, const float* __restrict__ huT4,
                 const float* __restrict__ h, const float* __restrict__ v,
                 float* __restrict__ out) {
    __shared__ float2 p2[LL];             // p2[j] = (p_q0, p_q1)   4 KB
    __shared__ float2 wsum[8];            // per-wave exp-sums
    __shared__ float red[8][2][DD];       // PV partials             8 KB

    int bx = blockIdx.x;
    int row0 = bx * 2;                    // global query rows row0, row0+1
    int b = bx >> 8;
    int t = threadIdx.x;
    int lane = t & 63;
    int w = __builtin_amdgcn_readfirstlane(t >> 6);   // uniform wave id

    // ---- phase 1: scores for both queries ----
    int j = w * 64 + lane;                // key index within batch
    int kk = b * LL + j;                  // global key row
    const float4* hp = (const float4*)huT4 + kk;      // stride NK float4s per d-group
    const float* sw0 = swB + (size_t)row0 * DD;       // uniform pointers -> s_load
    const float* sw1 = sw0 + DD;
    float acc0 = 0.f, acc1 = 0.f;
#pragma unroll 4
    for (int dg = 0; dg < 32; ++dg) {
        float4 hv = hp[(size_t)dg * NK];              // coalesced 1 KB/wave
        float4 s0 = *(const float4*)(sw0 + dg * 4);   // wave-uniform (scalar pipe)
        float4 s1 = *(const float4*)(sw1 + dg * 4);
        float4 vv = *(const float4*)(v   + dg * 4);
        acc0 = fmaf(vv.x, __builtin_amdgcn_rcpf(__expf(s0.x + hv.x) + 1.f), acc0);
        acc0 = fmaf(vv.y, __builtin_amdgcn_rcpf(__expf(s0.y + hv.y) + 1.f), acc0);
        acc0 = fmaf(vv.z, __builtin_amdgcn_rcpf(__expf(s0.z + hv.z) + 1.f), acc0);
        acc0 = fmaf(vv.w, __builtin_amdgcn_rcpf(__expf(s0.w + hv.w) + 1.f), acc0);
        acc1 = fmaf(vv.x, __builtin_amdgcn_rcpf(__expf(s1.x + hv.x) + 1.f), acc1);
        acc1 = fmaf(vv.y, __builtin_amdgcn_rcpf(__expf(s1.y + hv.y) + 1.f), acc1);
        acc1 = fmaf(vv.z, __builtin_amdgcn_rcpf(__expf(s1.z + hv.z) + 1.f), acc1);
        acc1 = fmaf(vv.w, __builtin_amdgcn_rcpf(__expf(s1.w + hv.w) + 1.f), acc1);
    }
    // score = SUM_d v_d*tanh(.) = V0 - 2*acc; V0 is query/key-independent ->
    // softmax-invariant, dropped. p = exp(-2*acc). |2*acc| <= ~9, fp32-safe.
    float p0 = __expf(-2.f * acc0);
    float p1 = __expf(-2.f * acc1);
    p2[j] = make_float2(p0, p1);
    float sm0 = p0, sm1 = p1;
#pragma unroll
    for (int o = 1; o < 64; o <<= 1) {
        sm0 += __shfl_xor(sm0, o);
        sm1 += __shfl_xor(sm1, o);
    }
    if (lane == 0) wsum[w] = make_float2(sm0, sm1);
    __syncthreads();

    // ---- phase 3: PV. Wave w: keys [w*64,+64), 2 keys/iter (halves), lane d4.
    int half = lane >> 5;
    int d4 = (lane & 31) * 4;
    const float* hb = h + (size_t)b * LL * DD;
    float4 a0 = make_float4(0.f, 0.f, 0.f, 0.f);
    float4 a1 = make_float4(0.f, 0.f, 0.f, 0.f);
#pragma unroll 4
    for (int jj = 0; jj < 32; ++jj) {
        int jl = w * 64 + jj * 2 + half;
        float4 hv = *(const float4*)&hb[jl * DD + d4];   // contiguous 1 KB/wave
        float2 pp = p2[jl];                               // 2-addr broadcast
        a0.x = fmaf(pp.x, hv.x, a0.x);  a1.x = fmaf(pp.y, hv.x, a1.x);
        a0.y = fmaf(pp.x, hv.y, a0.y);  a1.y = fmaf(pp.y, hv.y, a1.y);
        a0.z = fmaf(pp.x, hv.z, a0.z);  a1.z = fmaf(pp.y, hv.z, a1.z);
        a0.w = fmaf(pp.x, hv.w, a0.w);  a1.w = fmaf(pp.y, hv.w, a1.w);
    }
    // fold the two halves (different keys, same (q,d))
    a0.x += __shfl_xor(a0.x, 32);  a0.y += __shfl_xor(a0.y, 32);
    a0.z += __shfl_xor(a0.z, 32);  a0.w += __shfl_xor(a0.w, 32);
    a1.x += __shfl_xor(a1.x, 32);  a1.y += __shfl_xor(a1.y, 32);
    a1.z += __shfl_xor(a1.z, 32);  a1.w += __shfl_xor(a1.w, 32);
    if (half == 0) {
        *(float4*)&red[w][0][d4] = a0;
        *(float4*)&red[w][1][d4] = a1;
    }
    __syncthreads();

    // ---- epilogue: sum 8 wave-partials, normalize, store ----
    if (t < 256) {
        int q = t >> 7, d = t & 127;
        float o = 0.f;
#pragma unroll
        for (int k = 0; k < 8; ++k) o += red[k][q][d];
        float qs = 0.f;
#pragma unroll
        for (int k = 0; k < 8; ++k) qs += (q == 0) ? wsum[k].x : wsum[k].y;
        out[(size_t)(row0 + q) * DD + d] = o * __builtin_amdgcn_rcpf(qs);
    }
}

extern "C" void kernel_launch(void* const* d_in, const int* in_sizes, int n_in,
                              void* d_out, int out_size, void* d_ws, size_t ws_size,
                              hipStream_t stream) {
    const float* s = (const float*)d_in[0];
    const float* h = (const float*)d_in[1];
    const float* W = (const float*)d_in[2];
    const float* U = (const float*)d_in[3];
    const float* v = (const float*)d_in[4];
    float* out = (float*)d_out;
    float* ws  = (float*)d_ws;

    float* swB  = ws;                     // 1024*128 floats (2*s@W)
    float* huT4 = ws + 131072;            // 1024*128 floats (2*h@U, tiled)

    hipLaunchKernelGGL(proj_kernel, dim3(512), dim3(256), 0, stream,
                       s, h, W, U, swB, huT4);
    hipLaunchKernelGGL(attn_kernel, dim3(NK / 2), dim3(512), 0, stream,
                       swB, huT4, h, v, out);
}

// Round 5
// 80.522 us; speedup vs baseline: 1.3267x; 1.0692x over previous
//
#include <hip/hip_runtime.h>

#define DD 128
#define LL 512
#define BB 2
#define NK (BB * LL)   // 1024 global rows

// ---- Kernel 1: Es = exp(2*s@W) row-major [NK][DD];
//                EhT4 = exp(2*h@U) tiled [d>>2][key][d&3].
// The 2x is folded into the LDS load of the x-row. 512 blocks x 256 thr.
__global__ __launch_bounds__(256)
void proj_kernel(const float* __restrict__ s, const float* __restrict__ h,
                 const float* __restrict__ W, const float* __restrict__ U,
                 float* __restrict__ Es, float* __restrict__ EhT4) {
    __shared__ float xr[4 * DD];
    int bx = blockIdx.x;
    bool second = bx >= 256;
    const float* X = second ? h : s;
    const float* M = second ? U : W;
    int row0 = (bx & 255) * 4;            // global row (b*L + i)
    int t = threadIdx.x;
    xr[t]       = 2.0f * X[row0 * DD + t];
    xr[t + 256] = 2.0f * X[row0 * DD + 256 + t];
    __syncthreads();
    int c = t & 127, g = t >> 7;
    const float* x0 = &xr[(2 * g) * DD];
    const float* x1 = &xr[(2 * g + 1) * DD];
    float a0 = 0.f, a1 = 0.f;
#pragma unroll 8
    for (int d = 0; d < DD; ++d) {
        float m = M[d * DD + c];          // coalesced, L2-resident
        a0 = fmaf(x0[d], m, a0);
        a1 = fmaf(x1[d], m, a1);
    }
    float e0 = __expf(a0);                // exp(2*proj), |arg| <~ 12: safe
    float e1 = __expf(a1);
    if (!second) {
        Es[(row0 + 2 * g) * DD + c]     = e0;
        Es[(row0 + 2 * g + 1) * DD + c] = e1;
    } else {
        int base = (c >> 2) * (NK * 4) + (c & 3);   // tiled transpose
        EhT4[base + (row0 + 2 * g) * 4]     = e0;
        EhT4[base + (row0 + 2 * g + 1) * 4] = e1;
    }
}

// ---- Kernel 2: fused attention. Block = 4 queries x all 512 keys, 512 thr.
// Wave w owns keys [w*64,+64), 1 key/lane. Per d-PAIR per query: one rcp.
//   v_x/(1+Ex) + v_y/(1+Ey) = [v_x*Ey + v_y*Ex + (v_x+v_y)] / [(1+Ex)(1+Ey)]
// with Ex = Es(q,d)*Eh(j,d) (exp precomputed; no exp in hot loop).
__global__ __launch_bounds__(512, 2)
void attn_kernel(const float* __restrict__ Es, const float* __restrict__ EhT4,
                 const float* __restrict__ h, const float* __restrict__ v,
                 float* __restrict__ out) {
    __shared__ float4 p4[LL];             // p per (key, 4 queries)   8 KB
    __shared__ float4 wsum4[8];           // per-wave exp-sums (4 q)
    __shared__ float red[8][4][DD];       // PV partials             16 KB

    int bx = blockIdx.x;                  // 0..255
    int row0 = bx * 4;                    // global query rows row0..row0+3
    int b = bx >> 7;
    int t = threadIdx.x;
    int lane = t & 63;
    int w = __builtin_amdgcn_readfirstlane(t >> 6);   // uniform wave id

    // ---- phase 1: scores for 4 queries, 1 key per lane ----
    int j = w * 64 + lane;                // key within batch
    int kk = b * LL + j;                  // global key row
    const float4* hp = (const float4*)EhT4 + kk;      // stride NK float4 per d-group
    const float* es0 = Es + (size_t)row0 * DD;        // uniform -> scalar loads
    float ac0 = 0.f, ac1 = 0.f, ac2 = 0.f, ac3 = 0.f; // num*r parts
    float cc0 = 0.f, cc1 = 0.f, cc2 = 0.f, cc3 = 0.f; // vsum*r parts
#pragma unroll 4
    for (int dg = 0; dg < 32; ++dg) {
        float4 E  = hp[(size_t)dg * NK];              // Eh, coalesced 1 KB/wave
        float4 q0 = *(const float4*)(es0 + 0 * DD + dg * 4);  // wave-uniform
        float4 q1 = *(const float4*)(es0 + 1 * DD + dg * 4);
        float4 q2 = *(const float4*)(es0 + 2 * DD + dg * 4);
        float4 q3 = *(const float4*)(es0 + 3 * DD + dg * 4);
        float4 vv = *(const float4*)(v + dg * 4);
        float vsxy = vv.x + vv.y;                     // scalar adds
        float vszw = vv.z + vv.w;
#define PAIR(eqx, eqy, Ehx, Ehy, vx, vy, vs, ACC, CCC)                    \
        {                                                                 \
            float Ex = eqx * Ehx;                                         \
            float Ey = eqy * Ehy;                                         \
            float uy = Ey + 1.f;                                          \
            float den = fmaf(Ex, uy, uy);                                 \
            float r = __builtin_amdgcn_rcpf(den);                         \
            float num = fmaf(vx, Ey, vy * Ex);                            \
            ACC = fmaf(num, r, ACC);                                      \
            CCC = fmaf(vs, r, CCC);                                       \
        }
        PAIR(q0.x, q0.y, E.x, E.y, vv.x, vv.y, vsxy, ac0, cc0)
        PAIR(q0.z, q0.w, E.z, E.w, vv.z, vv.w, vszw, ac0, cc0)
        PAIR(q1.x, q1.y, E.x, E.y, vv.x, vv.y, vsxy, ac1, cc1)
        PAIR(q1.z, q1.w, E.z, E.w, vv.z, vv.w, vszw, ac1, cc1)
        PAIR(q2.x, q2.y, E.x, E.y, vv.x, vv.y, vsxy, ac2, cc2)
        PAIR(q2.z, q2.w, E.z, E.w, vv.z, vv.w, vszw, ac2, cc2)
        PAIR(q3.x, q3.y, E.x, E.y, vv.x, vv.y, vsxy, ac3, cc3)
        PAIR(q3.z, q3.w, E.z, E.w, vv.z, vv.w, vszw, ac3, cc3)
#undef PAIR
    }
    // score = sum_d v_d*tanh = (const) - 2*acc; const is softmax-invariant.
    float p0 = __expf(-2.f * (ac0 + cc0));
    float p1 = __expf(-2.f * (ac1 + cc1));
    float p2 = __expf(-2.f * (ac2 + cc2));
    float p3 = __expf(-2.f * (ac3 + cc3));
    p4[j] = make_float4(p0, p1, p2, p3);
    float m0 = p0, m1 = p1, m2 = p2, m3 = p3;
#pragma unroll
    for (int o = 1; o < 64; o <<= 1) {
        m0 += __shfl_xor(m0, o);
        m1 += __shfl_xor(m1, o);
        m2 += __shfl_xor(m2, o);
        m3 += __shfl_xor(m3, o);
    }
    if (lane == 0) wsum4[w] = make_float4(m0, m1, m2, m3);
    __syncthreads();

    // ---- phase 3: PV. Wave w keys [w*64,+64), 2 keys/iter (halves), lane d4.
    int half = lane >> 5;
    int d4 = (lane & 31) * 4;
    const float* hb = h + (size_t)b * LL * DD;
    float4 A0 = make_float4(0.f, 0.f, 0.f, 0.f), A1 = A0, A2 = A0, A3 = A0;
#pragma unroll 4
    for (int jj = 0; jj < 32; ++jj) {
        int jl = w * 64 + jj * 2 + half;
        float4 hv = *(const float4*)&hb[jl * DD + d4];   // contiguous 1 KB/wave
        float4 pp = p4[jl];                               // b128 broadcast
        A0.x = fmaf(pp.x, hv.x, A0.x); A0.y = fmaf(pp.x, hv.y, A0.y);
        A0.z = fmaf(pp.x, hv.z, A0.z); A0.w = fmaf(pp.x, hv.w, A0.w);
        A1.x = fmaf(pp.y, hv.x, A1.x); A1.y = fmaf(pp.y, hv.y, A1.y);
        A1.z = fmaf(pp.y, hv.z, A1.z); A1.w = fmaf(pp.y, hv.w, A1.w);
        A2.x = fmaf(pp.z, hv.x, A2.x); A2.y = fmaf(pp.z, hv.y, A2.y);
        A2.z = fmaf(pp.z, hv.z, A2.z); A2.w = fmaf(pp.z, hv.w, A2.w);
        A3.x = fmaf(pp.w, hv.x, A3.x); A3.y = fmaf(pp.w, hv.y, A3.y);
        A3.z = fmaf(pp.w, hv.z, A3.z); A3.w = fmaf(pp.w, hv.w, A3.w);
    }
    // fold the two halves (different keys, same (q,d))
#define FOLD(A) A.x += __shfl_xor(A.x, 32); A.y += __shfl_xor(A.y, 32); \
                A.z += __shfl_xor(A.z, 32); A.w += __shfl_xor(A.w, 32);
    FOLD(A0) FOLD(A1) FOLD(A2) FOLD(A3)
#undef FOLD
    if (half == 0) {
        *(float4*)&red[w][0][d4] = A0;
        *(float4*)&red[w][1][d4] = A1;
        *(float4*)&red[w][2][d4] = A2;
        *(float4*)&red[w][3][d4] = A3;
    }
    __syncthreads();

    // ---- epilogue: sum 8 wave-partials, normalize, store ----
    {
        int q = t >> 7, d = t & 127;
        float o = 0.f;
#pragma unroll
        for (int k = 0; k < 8; ++k) o += red[k][q][d];
        const float* wf = (const float*)wsum4;
        float qs = 0.f;
#pragma unroll
        for (int k = 0; k < 8; ++k) qs += wf[k * 4 + q];
        out[(size_t)(row0 + q) * DD + d] = o * __builtin_amdgcn_rcpf(qs);
    }
}

extern "C" void kernel_launch(void* const* d_in, const int* in_sizes, int n_in,
                              void* d_out, int out_size, void* d_ws, size_t ws_size,
                              hipStream_t stream) {
    const float* s = (const float*)d_in[0];
    const float* h = (const float*)d_in[1];
    const float* W = (const float*)d_in[2];
    const float* U = (const float*)d_in[3];
    const float* v = (const float*)d_in[4];
    float* out = (float*)d_out;
    float* ws  = (float*)d_ws;

    float* Es   = ws;                     // 1024*128 floats: exp(2*s@W)
    float* EhT4 = ws + 131072;            // 1024*128 floats: exp(2*h@U), tiled

    hipLaunchKernelGGL(proj_kernel, dim3(512), dim3(256), 0, stream,
                       s, h, W, U, Es, EhT4);
    hipLaunchKernelGGL(attn_kernel, dim3(NK / 4), dim3(512), 0, stream,
                       Es, EhT4, h, v, out);
}